// Round 9
// baseline (174.657 us; speedup 1.0000x reference)
//
#include <hip/hip_runtime.h>
#include <hip/hip_bf16.h>

typedef __attribute__((ext_vector_type(8))) short bf16x8;
typedef __attribute__((ext_vector_type(8))) unsigned short u16x8;
typedef __attribute__((ext_vector_type(4))) unsigned short u16x4;
typedef __attribute__((ext_vector_type(4))) float f32x4;

__device__ __forceinline__ unsigned short f2bf(float f) {
    __hip_bfloat16 h = __float2bfloat16(f);
    return *reinterpret_cast<unsigned short*>(&h);
}

__device__ __forceinline__ void cp16(void* lds, const void* g) {
    __builtin_amdgcn_global_load_lds(
        (const __attribute__((address_space(1))) unsigned int*)g,
        (__attribute__((address_space(3))) unsigned int*)lds, 16, 0, 0);
}

// ---------------------------------------------------------------------------
// Kernel 1: pack W into FRAGMENT-MAJOR bf16 layout (r8, proven).
//   wtf[((ks*24 + nfrag)*64 + lane)*8 + j] = W[k][n],
//   n = nfrag*16 + (lane&15), k = ks*32 + (lane>>4)*8 + j.
// ---------------------------------------------------------------------------
__global__ __launch_bounds__(256) void pack_wf(
    const float* __restrict__ wq, const float* __restrict__ wk,
    const float* __restrict__ wv, unsigned short* __restrict__ wtf)
{
    int idx  = blockIdx.x * 256 + threadIdx.x;   // 98304 = 64*24*64
    int lane = idx & 63;
    int rest = idx >> 6;
    int nfrag = rest % 24;
    int ks    = rest / 24;
    int cl = lane & 15, grp = lane >> 4;
    int n   = nfrag * 16 + cl;
    int sel = n >> 7, h = n & 127;
    const float* w = (sel == 0) ? wq : (sel == 1) ? wk : wv;
    int k0 = ks * 32 + grp * 8;
    u16x8 u;
    #pragma unroll
    for (int j = 0; j < 8; ++j) u[j] = f2bf(w[(size_t)(k0 + j) * 128 + h]);
    *reinterpret_cast<u16x8*>(wtf + (size_t)idx * 8) = u;
}

// ---------------------------------------------------------------------------
// Kernel 2: QKV GEMM — no LDS, no barriers, MAX TLP.
//   1024 blocks x 256 thr = 4 blocks/CU, 16 waves/CU (4/SIMD).
//   Block owns 16 M-rows x all 384 N; wave w owns n-range [w*96, +96).
//   The 4 waves read the SAME 16 x-rows -> per-CU L1 dedups (2 KB/step).
//   A: direct fp32 loads + in-register cvt (r5/r8-verified pattern).
//   B: fragment-major wtf, 1-KB contiguous coalesced per wave-load, L2-hot.
//   No syncs -> waves slip freely; 16 streams/CU hide L2/L3 latency.
//   Epilogue: RoPE Q/K (K bank-swizzled), V transposed+swizzled (proven).
// ---------------------------------------------------------------------------
__global__ __launch_bounds__(256, 4) void qkv_gemm(
    const float* __restrict__ x, const unsigned short* __restrict__ wtf,
    const float* __restrict__ rc, const float* __restrict__ rs,
    unsigned short* __restrict__ Qb, unsigned short* __restrict__ Kb,
    unsigned short* __restrict__ VT)
{
    const int mtile = blockIdx.x;          // 0..1023
    const int tid  = threadIdx.x;
    const int lane = tid & 63;
    const int w    = tid >> 6;             // 0..3
    const int grp  = lane >> 4, cl = lane & 15;

    const float* xb = x + (size_t)(mtile * 16) * 2048;

    const f32x4 fz = {0.f, 0.f, 0.f, 0.f};
    f32x4 acc[6];
    #pragma unroll
    for (int nf = 0; nf < 6; ++nf) acc[nf] = fz;

    const float* ap0 = xb + (size_t)cl * 2048 + grp * 8;

    for (int ks = 0; ks < 64; ++ks) {
        const float* ap = ap0 + ks * 32;
        f32x4 lo = *reinterpret_cast<const f32x4*>(ap);
        f32x4 hi = *reinterpret_cast<const f32x4*>(ap + 4);

        const unsigned short* bp =
            wtf + ((size_t)(ks * 24 + w * 6) * 64 + lane) * 8;
        bf16x8 b[6];
        #pragma unroll
        for (int nf = 0; nf < 6; ++nf)
            b[nf] = *reinterpret_cast<const bf16x8*>(bp + nf * 512);

        bf16x8 a;
        a[0] = (short)f2bf(lo[0]); a[1] = (short)f2bf(lo[1]);
        a[2] = (short)f2bf(lo[2]); a[3] = (short)f2bf(lo[3]);
        a[4] = (short)f2bf(hi[0]); a[5] = (short)f2bf(hi[1]);
        a[6] = (short)f2bf(hi[2]); a[7] = (short)f2bf(hi[3]);

        #pragma unroll
        for (int nf = 0; nf < 6; ++nf)
            acc[nf] = __builtin_amdgcn_mfma_f32_16x16x32_bf16(
                a, b[nf], acc[nf], 0, 0, 0);
    }

    // Epilogue. C-layout: col = lane&15, row = (lane>>4)*4 + r
    {
        int mrow = mtile * 16 + grp * 4;
        int bb   = mrow >> 11;
        #pragma unroll
        for (int nf = 0; nf < 6; ++nf) {
            int nbase = w * 96 + nf * 16;
            int sel   = nbase >> 7;            // 0=Q 1=K 2=V
            int h     = (nbase & 127) + cl;
            if (sel < 2) {
                #pragma unroll
                for (int r = 0; r < 4; ++r) {
                    int   m   = mrow + r;
                    int   tr  = m & 2047;
                    float val = acc[nf][r];
                    float pr  = __shfl_xor(val, 1, 64);
                    float cs  = rc[tr * 128 + h];
                    float sn  = rs[tr * 128 + h];
                    float res = (h & 1) ? fmaf(val, cs, pr * sn)
                                        : fmaf(val, cs, -pr * sn);
                    if (sel == 0) {
                        Qb[(size_t)m * 128 + h] = f2bf(res);
                    } else {
                        int bo = h * 2;
                        int bs = (bo & 128) | ((bo & 127) ^ ((m & 7) << 4));
                        *(unsigned short*)((char*)Kb + (size_t)m * 256 + bs) = f2bf(res);
                    }
                }
            } else {
                u16x4 pk;
                #pragma unroll
                for (int r = 0; r < 4; ++r) pk[r] = f2bf(acc[nf][r]);
                int t0 = mrow & 2047;
                int bo = (t0 * 2) & 127;
                int bs = ((t0 * 2) & ~127) | (bo ^ ((h & 7) << 4));
                *reinterpret_cast<u16x4*>(
                    (char*)VT + (size_t)(bb * 128 + h) * 4096 + bs) = pk;
            }
        }
    }
}

// ---------------------------------------------------------------------------
// Kernel 3: causal flash attention (proven round-2 version, unchanged).
// ---------------------------------------------------------------------------
__global__ __launch_bounds__(256, 2) void flash_attn(
    const unsigned short* __restrict__ Qb, const unsigned short* __restrict__ Kb,
    const unsigned short* __restrict__ VT, float* __restrict__ Op,
    float2* __restrict__ ML, float* __restrict__ out, int nchunk)
{
    __shared__ __align__(16) unsigned short Ks[2][64 * 128];
    __shared__ __align__(16) unsigned short Vs[2][128 * 64];
    __shared__ __align__(16) unsigned short Ps[4][16 * 72];

    const int g      = blockIdx.x;
    const int per_mt = 8 * nchunk;
    const int mtd    = g / per_mt;
    const int mt     = 31 - mtd;
    const int rem    = g - mtd * per_mt;
    const int c      = rem >> 3;
    const int b      = rem & 7;

    const int tid  = threadIdx.x;
    const int lane = tid & 63;
    const int w    = tid >> 6;
    const int grp  = lane >> 4, cl = lane & 15;

    const int NT   = mt + 1;
    const int T0   = (NT + 1) >> 1;
    const int tbeg = (nchunk == 2 && c == 1) ? T0 : 0;
    const int tend = (nchunk == 2 && c == 0) ? T0 : NT;

    const int   q0    = mt * 64 + w * 16;
    const float scale = 0.08838834764831845f;

    bf16x8 aq[4];
    {
        const unsigned short* qp = Qb + (size_t)(b * 2048 + q0 + cl) * 128 + grp * 8;
        #pragma unroll
        for (int kc = 0; kc < 4; ++kc)
            aq[kc] = *reinterpret_cast<const bf16x8*>(qp + kc * 32);
    }

    const f32x4 fz = {0.f, 0.f, 0.f, 0.f};
    f32x4 o[8];
    #pragma unroll
    for (int nf = 0; nf < 8; ++nf) o[nf] = fz;
    float mrun[4], lrun[4];
    #pragma unroll
    for (int r = 0; r < 4; ++r) { mrun[r] = -INFINITY; lrun[r] = 0.f; }

    const char* kgb = (const char*)(Kb + (size_t)b * 2048 * 128);
    const char* vgb = (const char*)(VT + (size_t)b * 128 * 2048);

    auto stage = [&](int d, int t) {
        const char* ks = kgb + (size_t)t * 64 * 256;
        char* kd = (char*)&Ks[d][0];
        #pragma unroll
        for (int i = 0; i < 4; ++i) {
            int off = w * 4096 + i * 1024 + lane * 16;
            cp16(kd + off, ks + off);
        }
        const char* vsb = vgb + (size_t)t * 128;
        char* vd = (char*)&Vs[d][0];
        #pragma unroll
        for (int i = 0; i < 4; ++i) {
            int off = w * 4096 + i * 1024 + lane * 16;
            cp16(vd + off, vsb + (size_t)(off >> 7) * 4096 + (off & 127));
        }
    };

    if (tbeg < tend) stage(0, tbeg);
    __syncthreads();

    int cur = 0;
    for (int t = tbeg; t < tend; ++t) {
        if (t + 1 < tend) stage(cur ^ 1, t + 1);

        const char* kb   = (const char*)&Ks[cur][0];
        const char* vb   = (const char*)&Vs[cur][0];
        const bool  diag = (t == mt);
        const int   jmax = diag ? (w + 1) : 4;

        float p[4][4];
        float mx[4];
        #pragma unroll
        for (int r = 0; r < 4; ++r) mx[r] = -INFINITY;

        #pragma unroll
        for (int j = 0; j < 4; ++j) {
            #pragma unroll
            for (int r = 0; r < 4; ++r) p[j][r] = 0.f;
            if (j < jmax) {
                int   row = j * 16 + cl;
                f32x4 s   = fz;
                #pragma unroll
                for (int kc = 0; kc < 4; ++kc) {
                    int bo = kc * 64 + grp * 16;
                    int bs = (bo & 128) | ((bo & 127) ^ ((row & 7) << 4));
                    bf16x8 kf = *reinterpret_cast<const bf16x8*>(kb + row * 256 + bs);
                    s = __builtin_amdgcn_mfma_f32_16x16x32_bf16(aq[kc], kf, s, 0, 0, 0);
                }
                #pragma unroll
                for (int r = 0; r < 4; ++r) {
                    float a = s[r] * scale;
                    if (diag && j == w && cl > grp * 4 + r) a = -INFINITY;
                    p[j][r] = a;
                    mx[r]   = fmaxf(mx[r], a);
                }
            }
        }
        #pragma unroll
        for (int d = 1; d < 16; d <<= 1)
            #pragma unroll
            for (int r = 0; r < 4; ++r)
                mx[r] = fmaxf(mx[r], __shfl_xor(mx[r], d, 64));

        float alpha[4], psum[4];
        #pragma unroll
        for (int r = 0; r < 4; ++r) {
            float mn = fmaxf(mrun[r], mx[r]);
            alpha[r] = __expf(mrun[r] - mn);
            mrun[r]  = mn;
            psum[r]  = 0.f;
        }
        #pragma unroll
        for (int j = 0; j < 4; ++j)
            if (j < jmax)
                #pragma unroll
                for (int r = 0; r < 4; ++r) {
                    p[j][r] = __expf(p[j][r] - mrun[r]);
                    psum[r] += p[j][r];
                }
        #pragma unroll
        for (int d = 1; d < 16; d <<= 1)
            #pragma unroll
            for (int r = 0; r < 4; ++r)
                psum[r] += __shfl_xor(psum[r], d, 64);
        #pragma unroll
        for (int r = 0; r < 4; ++r)
            lrun[r] = lrun[r] * alpha[r] + psum[r];
        #pragma unroll
        for (int nf = 0; nf < 8; ++nf)
            #pragma unroll
            for (int r = 0; r < 4; ++r) o[nf][r] *= alpha[r];

        char* pwb = (char*)&Ps[w][0];
        #pragma unroll
        for (int j = 0; j < 4; ++j)
            #pragma unroll
            for (int r = 0; r < 4; ++r) {
                int prow = grp * 4 + r;
                int bytec = ((j * 16 + cl) * 2) ^ ((prow & 7) << 4);
                *reinterpret_cast<unsigned short*>(pwb + prow * 144 + bytec) =
                    f2bf(p[j][r]);
            }

        const char* pb = (const char*)&Ps[w][0];
        #pragma unroll
        for (int half = 0; half < 2; ++half) {
            int pbo = half * 64 + grp * 16;
            bf16x8 pa = *reinterpret_cast<const bf16x8*>(
                pb + cl * 144 + (pbo ^ ((cl & 7) << 4)));
            #pragma unroll
            for (int nf = 0; nf < 8; ++nf) {
                int h  = nf * 16 + cl;
                int bs = (half * 64 + grp * 16) ^ ((h & 7) << 4);
                bf16x8 vf = *reinterpret_cast<const bf16x8*>(vb + h * 128 + bs);
                o[nf] = __builtin_amdgcn_mfma_f32_16x16x32_bf16(pa, vf, o[nf], 0, 0, 0);
            }
        }
        __syncthreads();
        cur ^= 1;
    }

    if (nchunk == 2) {
        #pragma unroll
        for (int nf = 0; nf < 8; ++nf)
            #pragma unroll
            for (int r = 0; r < 4; ++r) {
                size_t rowg = (size_t)c * 16384 + b * 2048 + q0 + grp * 4 + r;
                Op[rowg * 128 + nf * 16 + cl] = o[nf][r];
            }
        if (cl == 0)
            #pragma unroll
            for (int r = 0; r < 4; ++r)
                ML[(size_t)c * 16384 + b * 2048 + q0 + grp * 4 + r] =
                    make_float2(mrun[r], lrun[r]);
    } else {
        float inv[4];
        #pragma unroll
        for (int r = 0; r < 4; ++r) inv[r] = 1.0f / lrun[r];
        #pragma unroll
        for (int nf = 0; nf < 8; ++nf)
            #pragma unroll
            for (int r = 0; r < 4; ++r)
                out[(size_t)(b * 2048 + q0 + grp * 4 + r) * 128 + nf * 16 + cl] =
                    o[nf][r] * inv[r];
    }
}

// ---------------------------------------------------------------------------
// Kernel 4: merge the 2 KV-chunk partials.
// ---------------------------------------------------------------------------
__global__ __launch_bounds__(256) void merge2(
    const float* __restrict__ Op, const float2* __restrict__ ML,
    float* __restrict__ out)
{
    int idx = blockIdx.x * 256 + threadIdx.x;
    int row = idx >> 5, hq = idx & 31;
    float2 ml0 = ML[row];
    float2 ml1 = ML[16384 + row];
    float  m  = fmaxf(ml0.x, ml1.x);
    float  e0 = __expf(ml0.x - m);
    float  e1 = __expf(ml1.x - m);
    float  inv = 1.0f / (ml0.y * e0 + ml1.y * e1);
    f32x4 o0 = *reinterpret_cast<const f32x4*>(Op + (size_t)row * 128 + hq * 4);
    f32x4 o1 = *reinterpret_cast<const f32x4*>(Op + ((size_t)16384 + row) * 128 + hq * 4);
    f32x4 res;
    #pragma unroll
    for (int i = 0; i < 4; ++i) res[i] = (o0[i] * e0 + o1[i] * e1) * inv;
    *reinterpret_cast<f32x4*>(out + (size_t)row * 128 + hq * 4) = res;
}

// ---------------------------------------------------------------------------
extern "C" void kernel_launch(void* const* d_in, const int* in_sizes, int n_in,
                              void* d_out, int out_size, void* d_ws, size_t ws_size,
                              hipStream_t stream)
{
    const float* x  = (const float*)d_in[0];
    const float* wq = (const float*)d_in[1];
    const float* wk = (const float*)d_in[2];
    const float* wv = (const float*)d_in[3];
    const float* rc = (const float*)d_in[4];
    const float* rs = (const float*)d_in[5];
    float* out = (float*)d_out;

    char* ws = (char*)d_ws;
    const size_t MB = 1u << 20;
    unsigned short* wtf = (unsigned short*)(ws);             // 1.5 MB
    unsigned short* Qb  = (unsigned short*)(ws + 2 * MB);    // 4 MB
    unsigned short* Kb  = (unsigned short*)(ws + 6 * MB);    // 4 MB
    unsigned short* VT  = (unsigned short*)(ws + 10 * MB);   // 4 MB
    float*          Op  = (float*)        (ws + 14 * MB);    // 16 MB
    float2*         ML  = (float2*)       (ws + 30 * MB);    // 256 KB

    const int nchunk = (ws_size >= (size_t)31 * MB) ? 2 : 1;

    pack_wf <<<384,  256, 0, stream>>>(wq, wk, wv, wtf);
    qkv_gemm<<<1024, 256, 0, stream>>>(x, wtf, rc, rs, Qb, Kb, VT);
    flash_attn<<<32 * 8 * nchunk, 256, 0, stream>>>(Qb, Kb, VT, Op, ML, out, nchunk);
    if (nchunk == 2)
        merge2<<<2048, 256, 0, stream>>>(Op, ML, out);
}

// Round 10
// 106.972 us; speedup vs baseline: 1.6327x; 1.6327x over previous
//
#include <hip/hip_runtime.h>
#include <hip/hip_bf16.h>

typedef __attribute__((ext_vector_type(8))) short bf16x8;
typedef __attribute__((ext_vector_type(8))) unsigned short u16x8;
typedef __attribute__((ext_vector_type(4))) unsigned short u16x4;
typedef __attribute__((ext_vector_type(4))) float f32x4;

__device__ __forceinline__ unsigned short f2bf(float f) {
    __hip_bfloat16 h = __float2bfloat16(f);
    return *reinterpret_cast<unsigned short*>(&h);
}

__device__ __forceinline__ void cp16(void* lds, const void* g) {
    __builtin_amdgcn_global_load_lds(
        (const __attribute__((address_space(1))) unsigned int*)g,
        (__attribute__((address_space(3))) unsigned int*)lds, 16, 0, 0);
}

// ---------------------------------------------------------------------------
// Kernel 1: pack W^T bf16: wt[(sel*128+n)*2048 + k] = w_sel[k*128 + n]
// ---------------------------------------------------------------------------
__global__ __launch_bounds__(256) void pack_w(
    const float* __restrict__ wq, const float* __restrict__ wk,
    const float* __restrict__ wv, unsigned short* __restrict__ wt)
{
    int idx = blockIdx.x * 256 + threadIdx.x;
    int n   = idx & 127;
    int k   = (idx >> 7) & 2047;
    int sel = idx >> 18;
    const float* w = (sel == 0) ? wq : (sel == 1) ? wk : wv;
    wt[(size_t)(sel * 128 + n) * 2048 + k] = f2bf(w[k * 128 + n]);
}

// ---------------------------------------------------------------------------
// Kernel 2: QKV GEMM = r2-mono (proven 92 us) + BK 32->64 (half the
//   barrier-steps: 64 -> 32/block) + m201-style XOR swizzle on both LDS
//   tiles (reg-staged, so write AND read sides swizzled; kills the 3.1M
//   bank conflicts). 128x128 tile, 4 waves (2x2), double-buffered 64 KB LDS,
//   one __syncthreads per step.
//   Epilogue: RoPE Q/K (K bank-swizzled), V transposed+swizzled (proven).
// ---------------------------------------------------------------------------
__global__ __launch_bounds__(256) void qkv_gemm(
    const float* __restrict__ x, const unsigned short* __restrict__ wt,
    const float* __restrict__ rc, const float* __restrict__ rs,
    unsigned short* __restrict__ Qb, unsigned short* __restrict__ Kb,
    unsigned short* __restrict__ VT)
{
    __shared__ __align__(16) unsigned short As[2][128 * 64];   // 16 KB x2
    __shared__ __align__(16) unsigned short Bs[2][128 * 64];   // 16 KB x2

    const int bid   = blockIdx.x;           // 384
    const int slot  = bid & 7;
    const int idx   = bid >> 3;             // 0..47
    const int mtile = slot + 8 * (idx / 3); // trio of ntiles shares XCD slot
    const int ntile = idx % 3;

    const int tid  = threadIdx.x;
    const int lane = tid & 63;
    const int wid  = tid >> 6;
    const int wm   = wid >> 1, wn = wid & 1;
    const int grp  = lane >> 4, cl = lane & 15;

    const int arow0 = tid >> 2;             // 0..63
    const int ak    = tid & 3;              // 16-float k-chunk within BK=64

    const float*          xbase = x  + (size_t)(mtile * 128) * 2048;
    const unsigned short* wbase = wt + (size_t)(ntile * 128) * 2048;

    float4 afl[2][4];
    u16x8  bwl[2][2];

    auto gload = [&](int ks) {
        int k0 = ks * 64 + ak * 16;
        #pragma unroll
        for (int i = 0; i < 2; ++i) {
            int row = arow0 + i * 64;
            const float* p = xbase + (size_t)row * 2048 + k0;
            afl[i][0] = *reinterpret_cast<const float4*>(p);
            afl[i][1] = *reinterpret_cast<const float4*>(p + 4);
            afl[i][2] = *reinterpret_cast<const float4*>(p + 8);
            afl[i][3] = *reinterpret_cast<const float4*>(p + 12);
            const unsigned short* q = wbase + (size_t)row * 2048 + k0;
            bwl[i][0] = *reinterpret_cast<const u16x8*>(q);
            bwl[i][1] = *reinterpret_cast<const u16x8*>(q + 8);
        }
    };
    auto swrite = [&](int buf) {
        #pragma unroll
        for (int i = 0; i < 2; ++i) {
            int row = arow0 + i * 64;
            int sw  = row & 7;
            #pragma unroll
            for (int j = 0; j < 2; ++j) {
                u16x8 u;
                const float4 f0 = afl[i][2 * j];
                const float4 f1 = afl[i][2 * j + 1];
                u[0] = f2bf(f0.x); u[1] = f2bf(f0.y);
                u[2] = f2bf(f0.z); u[3] = f2bf(f0.w);
                u[4] = f2bf(f1.x); u[5] = f2bf(f1.y);
                u[6] = f2bf(f1.z); u[7] = f2bf(f1.w);
                int c = (ak * 2 + j) ^ sw;       // XOR-swizzled 16B chunk
                *reinterpret_cast<u16x8*>(
                    (char*)&As[buf][0] + row * 128 + c * 16) = u;
                *reinterpret_cast<u16x8*>(
                    (char*)&Bs[buf][0] + row * 128 + c * 16) = bwl[i][j];
            }
        }
    };

    const f32x4 fz = {0.f, 0.f, 0.f, 0.f};
    f32x4 acc[4][4];
    #pragma unroll
    for (int mf = 0; mf < 4; ++mf)
        #pragma unroll
        for (int nf = 0; nf < 4; ++nf) acc[mf][nf] = fz;

    gload(0);
    swrite(0);
    __syncthreads();

    for (int ks = 0; ks < 32; ++ks) {
        int cur = ks & 1;
        if (ks < 31) gload(ks + 1);

        #pragma unroll
        for (int half = 0; half < 2; ++half) {
            bf16x8 a[4], b[4];
            #pragma unroll
            for (int mf = 0; mf < 4; ++mf) {
                int row = wm * 64 + mf * 16 + cl;
                int c   = (half * 4 + grp) ^ (row & 7);
                a[mf] = *reinterpret_cast<const bf16x8*>(
                    (const char*)&As[cur][0] + row * 128 + c * 16);
            }
            #pragma unroll
            for (int nf = 0; nf < 4; ++nf) {
                int n = wn * 64 + nf * 16 + cl;
                int c = (half * 4 + grp) ^ (n & 7);
                b[nf] = *reinterpret_cast<const bf16x8*>(
                    (const char*)&Bs[cur][0] + n * 128 + c * 16);
            }
            #pragma unroll
            for (int mf = 0; mf < 4; ++mf)
                #pragma unroll
                for (int nf = 0; nf < 4; ++nf)
                    acc[mf][nf] = __builtin_amdgcn_mfma_f32_16x16x32_bf16(
                        a[mf], b[nf], acc[mf][nf], 0, 0, 0);
        }

        if (ks < 31) swrite(cur ^ 1);
        __syncthreads();
    }

    // Epilogue. C-layout: col = lane&15, row = (lane>>4)*4 + r
    if (ntile == 0) {
        #pragma unroll
        for (int mf = 0; mf < 4; ++mf) {
            int mrow = mtile * 128 + wm * 64 + mf * 16 + grp * 4;
            #pragma unroll
            for (int nf = 0; nf < 4; ++nf) {
                int h = wn * 64 + nf * 16 + cl;
                #pragma unroll
                for (int r = 0; r < 4; ++r) {
                    int   m   = mrow + r;
                    int   t   = m & 2047;
                    float val = acc[mf][nf][r];
                    float pr  = __shfl_xor(val, 1, 64);
                    float cs  = rc[t * 128 + h];
                    float sn  = rs[t * 128 + h];
                    float res = (h & 1) ? fmaf(val, cs, pr * sn)
                                        : fmaf(val, cs, -pr * sn);
                    Qb[(size_t)m * 128 + h] = f2bf(res);
                }
            }
        }
    } else if (ntile == 1) {
        #pragma unroll
        for (int mf = 0; mf < 4; ++mf) {
            int mrow = mtile * 128 + wm * 64 + mf * 16 + grp * 4;
            #pragma unroll
            for (int nf = 0; nf < 4; ++nf) {
                int h = wn * 64 + nf * 16 + cl;
                #pragma unroll
                for (int r = 0; r < 4; ++r) {
                    int   m   = mrow + r;
                    int   t   = m & 2047;
                    float val = acc[mf][nf][r];
                    float pr  = __shfl_xor(val, 1, 64);
                    float cs  = rc[t * 128 + h];
                    float sn  = rs[t * 128 + h];
                    float res = (h & 1) ? fmaf(val, cs, pr * sn)
                                        : fmaf(val, cs, -pr * sn);
                    int bo = h * 2;
                    int bs = (bo & 128) | ((bo & 127) ^ ((m & 7) << 4));
                    *(unsigned short*)((char*)Kb + (size_t)m * 256 + bs) = f2bf(res);
                }
            }
        }
    } else {
        #pragma unroll
        for (int mf = 0; mf < 4; ++mf) {
            int mrow = mtile * 128 + wm * 64 + mf * 16 + grp * 4;
            int bb   = mrow >> 11;
            int t0   = mrow & 2047;
            #pragma unroll
            for (int nf = 0; nf < 4; ++nf) {
                int h = wn * 64 + nf * 16 + cl;
                u16x4 pk;
                #pragma unroll
                for (int r = 0; r < 4; ++r) pk[r] = f2bf(acc[mf][nf][r]);
                int bo = (t0 * 2) & 127;
                int bs = ((t0 * 2) & ~127) | (bo ^ ((h & 7) << 4));
                *reinterpret_cast<u16x4*>(
                    (char*)VT + (size_t)(bb * 128 + h) * 4096 + bs) = pk;
            }
        }
    }
}

// ---------------------------------------------------------------------------
// Kernel 3: causal flash attention (proven round-2 version, unchanged).
// ---------------------------------------------------------------------------
__global__ __launch_bounds__(256, 2) void flash_attn(
    const unsigned short* __restrict__ Qb, const unsigned short* __restrict__ Kb,
    const unsigned short* __restrict__ VT, float* __restrict__ Op,
    float2* __restrict__ ML, float* __restrict__ out, int nchunk)
{
    __shared__ __align__(16) unsigned short Ks[2][64 * 128];
    __shared__ __align__(16) unsigned short Vs[2][128 * 64];
    __shared__ __align__(16) unsigned short Ps[4][16 * 72];

    const int g      = blockIdx.x;
    const int per_mt = 8 * nchunk;
    const int mtd    = g / per_mt;
    const int mt     = 31 - mtd;
    const int rem    = g - mtd * per_mt;
    const int c      = rem >> 3;
    const int b      = rem & 7;

    const int tid  = threadIdx.x;
    const int lane = tid & 63;
    const int w    = tid >> 6;
    const int grp  = lane >> 4, cl = lane & 15;

    const int NT   = mt + 1;
    const int T0   = (NT + 1) >> 1;
    const int tbeg = (nchunk == 2 && c == 1) ? T0 : 0;
    const int tend = (nchunk == 2 && c == 0) ? T0 : NT;

    const int   q0    = mt * 64 + w * 16;
    const float scale = 0.08838834764831845f;

    bf16x8 aq[4];
    {
        const unsigned short* qp = Qb + (size_t)(b * 2048 + q0 + cl) * 128 + grp * 8;
        #pragma unroll
        for (int kc = 0; kc < 4; ++kc)
            aq[kc] = *reinterpret_cast<const bf16x8*>(qp + kc * 32);
    }

    const f32x4 fz = {0.f, 0.f, 0.f, 0.f};
    f32x4 o[8];
    #pragma unroll
    for (int nf = 0; nf < 8; ++nf) o[nf] = fz;
    float mrun[4], lrun[4];
    #pragma unroll
    for (int r = 0; r < 4; ++r) { mrun[r] = -INFINITY; lrun[r] = 0.f; }

    const char* kgb = (const char*)(Kb + (size_t)b * 2048 * 128);
    const char* vgb = (const char*)(VT + (size_t)b * 128 * 2048);

    auto stage = [&](int d, int t) {
        const char* ks = kgb + (size_t)t * 64 * 256;
        char* kd = (char*)&Ks[d][0];
        #pragma unroll
        for (int i = 0; i < 4; ++i) {
            int off = w * 4096 + i * 1024 + lane * 16;
            cp16(kd + off, ks + off);
        }
        const char* vsb = vgb + (size_t)t * 128;
        char* vd = (char*)&Vs[d][0];
        #pragma unroll
        for (int i = 0; i < 4; ++i) {
            int off = w * 4096 + i * 1024 + lane * 16;
            cp16(vd + off, vsb + (size_t)(off >> 7) * 4096 + (off & 127));
        }
    };

    if (tbeg < tend) stage(0, tbeg);
    __syncthreads();

    int cur = 0;
    for (int t = tbeg; t < tend; ++t) {
        if (t + 1 < tend) stage(cur ^ 1, t + 1);

        const char* kb   = (const char*)&Ks[cur][0];
        const char* vb   = (const char*)&Vs[cur][0];
        const bool  diag = (t == mt);
        const int   jmax = diag ? (w + 1) : 4;

        float p[4][4];
        float mx[4];
        #pragma unroll
        for (int r = 0; r < 4; ++r) mx[r] = -INFINITY;

        #pragma unroll
        for (int j = 0; j < 4; ++j) {
            #pragma unroll
            for (int r = 0; r < 4; ++r) p[j][r] = 0.f;
            if (j < jmax) {
                int   row = j * 16 + cl;
                f32x4 s   = fz;
                #pragma unroll
                for (int kc = 0; kc < 4; ++kc) {
                    int bo = kc * 64 + grp * 16;
                    int bs = (bo & 128) | ((bo & 127) ^ ((row & 7) << 4));
                    bf16x8 kf = *reinterpret_cast<const bf16x8*>(kb + row * 256 + bs);
                    s = __builtin_amdgcn_mfma_f32_16x16x32_bf16(aq[kc], kf, s, 0, 0, 0);
                }
                #pragma unroll
                for (int r = 0; r < 4; ++r) {
                    float a = s[r] * scale;
                    if (diag && j == w && cl > grp * 4 + r) a = -INFINITY;
                    p[j][r] = a;
                    mx[r]   = fmaxf(mx[r], a);
                }
            }
        }
        #pragma unroll
        for (int d = 1; d < 16; d <<= 1)
            #pragma unroll
            for (int r = 0; r < 4; ++r)
                mx[r] = fmaxf(mx[r], __shfl_xor(mx[r], d, 64));

        float alpha[4], psum[4];
        #pragma unroll
        for (int r = 0; r < 4; ++r) {
            float mn = fmaxf(mrun[r], mx[r]);
            alpha[r] = __expf(mrun[r] - mn);
            mrun[r]  = mn;
            psum[r]  = 0.f;
        }
        #pragma unroll
        for (int j = 0; j < 4; ++j)
            if (j < jmax)
                #pragma unroll
                for (int r = 0; r < 4; ++r) {
                    p[j][r] = __expf(p[j][r] - mrun[r]);
                    psum[r] += p[j][r];
                }
        #pragma unroll
        for (int d = 1; d < 16; d <<= 1)
            #pragma unroll
            for (int r = 0; r < 4; ++r)
                psum[r] += __shfl_xor(psum[r], d, 64);
        #pragma unroll
        for (int r = 0; r < 4; ++r)
            lrun[r] = lrun[r] * alpha[r] + psum[r];
        #pragma unroll
        for (int nf = 0; nf < 8; ++nf)
            #pragma unroll
            for (int r = 0; r < 4; ++r) o[nf][r] *= alpha[r];

        char* pwb = (char*)&Ps[w][0];
        #pragma unroll
        for (int j = 0; j < 4; ++j)
            #pragma unroll
            for (int r = 0; r < 4; ++r) {
                int prow = grp * 4 + r;
                int bytec = ((j * 16 + cl) * 2) ^ ((prow & 7) << 4);
                *reinterpret_cast<unsigned short*>(pwb + prow * 144 + bytec) =
                    f2bf(p[j][r]);
            }

        const char* pb = (const char*)&Ps[w][0];
        #pragma unroll
        for (int half = 0; half < 2; ++half) {
            int pbo = half * 64 + grp * 16;
            bf16x8 pa = *reinterpret_cast<const bf16x8*>(
                pb + cl * 144 + (pbo ^ ((cl & 7) << 4)));
            #pragma unroll
            for (int nf = 0; nf < 8; ++nf) {
                int h  = nf * 16 + cl;
                int bs = (half * 64 + grp * 16) ^ ((h & 7) << 4);
                bf16x8 vf = *reinterpret_cast<const bf16x8*>(vb + h * 128 + bs);
                o[nf] = __builtin_amdgcn_mfma_f32_16x16x32_bf16(pa, vf, o[nf], 0, 0, 0);
            }
        }
        __syncthreads();
        cur ^= 1;
    }

    if (nchunk == 2) {
        #pragma unroll
        for (int nf = 0; nf < 8; ++nf)
            #pragma unroll
            for (int r = 0; r < 4; ++r) {
                size_t rowg = (size_t)c * 16384 + b * 2048 + q0 + grp * 4 + r;
                Op[rowg * 128 + nf * 16 + cl] = o[nf][r];
            }
        if (cl == 0)
            #pragma unroll
            for (int r = 0; r < 4; ++r)
                ML[(size_t)c * 16384 + b * 2048 + q0 + grp * 4 + r] =
                    make_float2(mrun[r], lrun[r]);
    } else {
        float inv[4];
        #pragma unroll
        for (int r = 0; r < 4; ++r) inv[r] = 1.0f / lrun[r];
        #pragma unroll
        for (int nf = 0; nf < 8; ++nf)
            #pragma unroll
            for (int r = 0; r < 4; ++r)
                out[(size_t)(b * 2048 + q0 + grp * 4 + r) * 128 + nf * 16 + cl] =
                    o[nf][r] * inv[r];
    }
}

// ---------------------------------------------------------------------------
// Kernel 4: merge the 2 KV-chunk partials.
// ---------------------------------------------------------------------------
__global__ __launch_bounds__(256) void merge2(
    const float* __restrict__ Op, const float2* __restrict__ ML,
    float* __restrict__ out)
{
    int idx = blockIdx.x * 256 + threadIdx.x;
    int row = idx >> 5, hq = idx & 31;
    float2 ml0 = ML[row];
    float2 ml1 = ML[16384 + row];
    float  m  = fmaxf(ml0.x, ml1.x);
    float  e0 = __expf(ml0.x - m);
    float  e1 = __expf(ml1.x - m);
    float  inv = 1.0f / (ml0.y * e0 + ml1.y * e1);
    f32x4 o0 = *reinterpret_cast<const f32x4*>(Op + (size_t)row * 128 + hq * 4);
    f32x4 o1 = *reinterpret_cast<const f32x4*>(Op + ((size_t)16384 + row) * 128 + hq * 4);
    f32x4 res;
    #pragma unroll
    for (int i = 0; i < 4; ++i) res[i] = (o0[i] * e0 + o1[i] * e1) * inv;
    *reinterpret_cast<f32x4*>(out + (size_t)row * 128 + hq * 4) = res;
}

// ---------------------------------------------------------------------------
extern "C" void kernel_launch(void* const* d_in, const int* in_sizes, int n_in,
                              void* d_out, int out_size, void* d_ws, size_t ws_size,
                              hipStream_t stream)
{
    const float* x  = (const float*)d_in[0];
    const float* wq = (const float*)d_in[1];
    const float* wk = (const float*)d_in[2];
    const float* wv = (const float*)d_in[3];
    const float* rc = (const float*)d_in[4];
    const float* rs = (const float*)d_in[5];
    float* out = (float*)d_out;

    char* ws = (char*)d_ws;
    const size_t MB = 1u << 20;
    unsigned short* wt = (unsigned short*)(ws);              // 1.5 MB
    unsigned short* Qb = (unsigned short*)(ws + 2 * MB);     // 4 MB
    unsigned short* Kb = (unsigned short*)(ws + 6 * MB);     // 4 MB
    unsigned short* VT = (unsigned short*)(ws + 10 * MB);    // 4 MB
    float*          Op = (float*)        (ws + 14 * MB);     // 16 MB
    float2*         ML = (float2*)       (ws + 30 * MB);     // 256 KB

    const int nchunk = (ws_size >= (size_t)31 * MB) ? 2 : 1;

    pack_w  <<<3072, 256, 0, stream>>>(wq, wk, wv, wt);
    qkv_gemm<<<384,  256, 0, stream>>>(x, wt, rc, rs, Qb, Kb, VT);
    flash_attn<<<32 * 8 * nchunk, 256, 0, stream>>>(Qb, Kb, VT, Op, ML, out, nchunk);
    if (nchunk == 2)
        merge2<<<2048, 256, 0, stream>>>(Op, ML, out);
}